// Round 6
// baseline (277.099 us; speedup 1.0000x reference)
//
#include <hip/hip_runtime.h>
#include <hip/hip_bf16.h>
#include <math.h>

constexpr int NB = 256;    // batch
constexpr int NS = 512;    // source positions
constexpr int ND = 1024;   // hidden
constexpr int NV = 50257;  // vocab
constexpr int NTILES_V = (NV + 63) / 64;   // 786
constexpr int NTILES_D = ND / 64;          // 16
constexpr int BSTEP = 9216;                // bytes per (tile, kstep) packed B image

typedef __attribute__((ext_vector_type(8))) short bf16x8;
typedef __attribute__((ext_vector_type(4))) float f32x4;

__device__ __forceinline__ short f2bf(float f) {
  unsigned u = __builtin_bit_cast(unsigned, f);
  u = (u + 0x7FFFu + ((u >> 16) & 1u)) >> 16;   // RNE
  return (short)u;
}

// A-side swizzle (unchanged, proven): chunk position = slot ^ swz(row).
__device__ __forceinline__ int swz(int r) { return (r & 7) ^ ((r >> 3) & 1); }

__device__ __forceinline__ const bf16x8* fragA(const short* base, int r, int slot) {
  return reinterpret_cast<const bf16x8*>(
      reinterpret_cast<const char*>(base) + r * 128 + ((slot ^ swz(r)) << 4));
}

// B-side: pad-9 layout, row stride 144B; banks: (36n+4s)%32 -> 2-way max (free).
__device__ __forceinline__ const bf16x8* fragB(const short* base, int n, int slot) {
  return reinterpret_cast<const bf16x8*>(
      reinterpret_cast<const char*>(base) + n * 144 + (slot << 4));
}

__device__ __forceinline__ void async_copy16(const void* gsrc, void* ldsdst) {
  __builtin_amdgcn_global_load_lds(
      (const __attribute__((address_space(1))) unsigned int*)gsrc,
      (__attribute__((address_space(3))) unsigned int*)ldsdst, 16, 0, 0);
}

// ---------------------------------------------------------------------------
// prep_x: xb[m][kt][chunkpos] bf16, pre-swizzled for linear global_load_lds.
// ---------------------------------------------------------------------------
__global__ __launch_bounds__(256)
void prep_x(const float* __restrict__ x, short* __restrict__ xb) {
  int idx = blockIdx.x * 256 + threadIdx.x;      // 32768 chunks
  int m = idx >> 7, kt = (idx >> 3) & 15, slot = idx & 7;
  const float4* src = reinterpret_cast<const float4*>(x + m * ND + kt * 64 + slot * 8);
  float4 f0 = src[0], f1 = src[1];
  bf16x8 v = { f2bf(f0.x), f2bf(f0.y), f2bf(f0.z), f2bf(f0.w),
               f2bf(f1.x), f2bf(f1.y), f2bf(f1.z), f2bf(f1.w) };
  *reinterpret_cast<bf16x8*>(reinterpret_cast<char*>(xb) +
      m * 2048 + kt * 128 + ((slot ^ swz(m)) << 4)) = v;
}

// ---------------------------------------------------------------------------
// prep_w: repack W[1024][N] f32 row-major -> packed[tile][t][9216B] bf16 LDS
// images. Reads: each wave = one 256B row segment, fully coalesced; dense
// short-lived blocks cover rows contiguously (DRAM-page friendly).
// Image chunk (n, p): p<8 holds k-octet p of column n; p==8 is bank pad.
// ---------------------------------------------------------------------------
__global__ __launch_bounds__(256)
void prep_w(const float* __restrict__ W, short* __restrict__ packed, int N) {
  const int tile = blockIdx.x, t = blockIdx.y;
  const int tid = threadIdx.x;
  char* dst = reinterpret_cast<char*>(packed) +
      ((size_t)tile * 16 + t) * BSTEP;
  const int n = tid & 63;
  const int col = tile * 64 + n;
  const bool ok = col < N;
#pragma unroll
  for (int q = 0; q < 2; ++q) {
    int p = q * 4 + (tid >> 6);                  // wave-uniform row octet
    bf16x8 v = {};
    if (ok) {
      const float* src = W + (size_t)(t * 64 + p * 8) * N + col;
#pragma unroll
      for (int i = 0; i < 8; ++i) v[i] = f2bf(src[(size_t)i * N]);
    }
    *reinterpret_cast<bf16x8*>(dst + (n * 9 + p) * 16) = v;
  }
  if (tid < 64) {                                // pad slot p=8: zero-fill
    bf16x8 z = {};
    *reinterpret_cast<bf16x8*>(dst + (tid * 9 + 8) * 16) = z;
  }
}

// ---------------------------------------------------------------------------
// Packed MFMA GEMM: C[256,N] = act(x @ W + bias). BM=256, BN=64, BK=64.
// A: single-buffered DMA from xb (L2). B: double-buffered DMA from packed
// (contiguous 147KB/block stream). Counted per-wave vmcnt keeps next-step B
// in flight across the barrier. 4 waves, 50KB LDS -> 3 blocks/CU.
// ---------------------------------------------------------------------------
__device__ __forceinline__ void gloadA(const short* __restrict__ xb,
                                       int w, int lane, int t, short* AsN) {
#pragma unroll
  for (int j = 0; j < 8; ++j) {
    int chunk = (w * 8 + j) * 64 + lane;         // 0..2047
    int ml = chunk >> 3, p = chunk & 7;
    const char* src = reinterpret_cast<const char*>(xb) +
        (ml << 11) + (t << 7) + (p << 4);
    async_copy16(src, reinterpret_cast<char*>(AsN) + ((w * 8 + j) << 10));
  }
}

__device__ __forceinline__ void stageB(const char* __restrict__ pw, int w, int lane,
                                       int t, short* BsN) {
  if (w < 3) {
    const char* src = pw + (size_t)t * BSTEP;
#pragma unroll
    for (int j = 0; j < 3; ++j) {
      int c0 = (w * 3 + j) * 64;
      async_copy16(src + (c0 + lane) * 16,
                   reinterpret_cast<char*>(BsN) + c0 * 16);
    }
  }
}

__device__ __forceinline__ void computeStep(const short* A, const short* B,
                                            int w, int g, int c16, f32x4 acc[4][4]) {
#pragma unroll
  for (int kk = 0; kk < 2; ++kk) {
    int slot = kk * 4 + g;
    bf16x8 b[4];
#pragma unroll
    for (int ni = 0; ni < 4; ++ni) b[ni] = *fragB(B, ni * 16 + c16, slot);
#pragma unroll
    for (int mi = 0; mi < 4; ++mi) {
      bf16x8 a = *fragA(A, w * 64 + mi * 16 + c16, slot);
#pragma unroll
      for (int ni = 0; ni < 4; ++ni)
        acc[mi][ni] = __builtin_amdgcn_mfma_f32_16x16x32_bf16(a, b[ni], acc[mi][ni], 0, 0, 0);
    }
  }
}

template<bool GATE>
__global__ __launch_bounds__(256, 3)
void gemm_packed(const short* __restrict__ xb, const short* __restrict__ packedW,
                 const float* __restrict__ bias, float* __restrict__ Cout,
                 float* __restrict__ partials, int N, int ntiles) {
  __shared__ __align__(16) short As[256 * 64];   // 32 KB
  __shared__ __align__(16) short Bs[2][BSTEP / 2];  // 2 x 9216 B
  const int tid = threadIdx.x;
  const int lane = tid & 63, w = tid >> 6;
  const int g = lane >> 4, c16 = lane & 15;
  const int n0 = blockIdx.x * 64;
  const char* pw = reinterpret_cast<const char*>(packedW) +
      (size_t)blockIdx.x * 16 * BSTEP;

  f32x4 acc[4][4] = {};

  stageB(pw, w, lane, 0, Bs[0]);                 // prologue: B(0) in flight

#pragma unroll 1
  for (int t = 0; t < 16; ++t) {
    // barrier 1: all waves done reading As/Bs[cur] from step t-1.
    asm volatile("" ::: "memory");
    __builtin_amdgcn_s_barrier();
    asm volatile("" ::: "memory");

    gloadA(xb, w, lane, t, As);                  // 8 DMA (L2-resident xb)
    asm volatile("" ::: "memory");               // pin: A before B
    if (t < 15) stageB(pw, w, lane, t + 1, Bs[(t + 1) & 1]);  // 3 DMA, next buf

    // drain own A(t) + B(t); keep B(t+1) in flight (waves 0-2, t<15).
    if (w < 3 && t < 15)
      asm volatile("s_waitcnt vmcnt(3) lgkmcnt(0)" ::: "memory");
    else
      asm volatile("s_waitcnt vmcnt(0) lgkmcnt(0)" ::: "memory");
    __builtin_amdgcn_s_barrier();
    asm volatile("" ::: "memory");

    computeStep(As, Bs[t & 1], w, g, c16, acc);
  }

  // epilogue: C/D layout col = lane&15, row = (lane>>4)*4 + reg
#pragma unroll
  for (int mi = 0; mi < 4; ++mi) {
#pragma unroll
    for (int r = 0; r < 4; ++r) {
      int row = w * 64 + mi * 16 + g * 4 + r;
      float vals[4];
      float pm = -3.0e38f;
#pragma unroll
      for (int ni = 0; ni < 4; ++ni) {
        int col = n0 + ni * 16 + c16;
        bool ok2 = col < N;
        float bv = ok2 ? bias[col] : 0.f;
        float v = acc[mi][ni][r] + bv;
        if (GATE) v = tanhf(v);
        vals[ni] = v;
        if (ok2) {
          Cout[(size_t)row * N + col] = v;
          pm = fmaxf(pm, v);
        }
      }
      if (!GATE) {
        float ps = 0.f;
#pragma unroll
        for (int ni = 0; ni < 4; ++ni) {
          int col = n0 + ni * 16 + c16;
          if (col < N) ps += expf(vals[ni] - pm);
        }
#pragma unroll
        for (int o = 1; o < 16; o <<= 1) {
          float m2 = __shfl_xor(pm, o, 64);
          float s2 = __shfl_xor(ps, o, 64);
          float mn = fmaxf(pm, m2);
          ps = ps * expf(pm - mn) + s2 * expf(m2 - mn);
          pm = mn;
        }
        if (c16 == 0) {
          partials[((size_t)row * ntiles + blockIdx.x) * 2 + 0] = pm;
          partials[((size_t)row * ntiles + blockIdx.x) * 2 + 1] = ps;
        }
      }
    }
  }
}

// ---------------------------------------------------------------------------
// Fallback GEMM (R5 path, used only if ws_size can't hold packed W).
// ---------------------------------------------------------------------------
__device__ __forceinline__ void loadB_f(const float* __restrict__ W, int ldN, bool okc,
                                        int n0, int w, int lane, int t, float v[16]) {
#pragma unroll
  for (int i = 0; i < 16; ++i)
    v[i] = okc ? W[(size_t)(t * 64 + w * 16 + i) * ldN + n0 + lane] : 0.f;
}

__device__ __forceinline__ void transB_f(const float v[16], short* BsN, int w, int lane) {
  bf16x8 lo = { f2bf(v[0]), f2bf(v[1]), f2bf(v[2]), f2bf(v[3]),
                f2bf(v[4]), f2bf(v[5]), f2bf(v[6]), f2bf(v[7]) };
  bf16x8 hi = { f2bf(v[8]), f2bf(v[9]), f2bf(v[10]), f2bf(v[11]),
                f2bf(v[12]), f2bf(v[13]), f2bf(v[14]), f2bf(v[15]) };
  char* row = reinterpret_cast<char*>(BsN) + lane * 128;
  *reinterpret_cast<bf16x8*>(row + (((w * 2 + 0) ^ swz(lane)) << 4)) = lo;
  *reinterpret_cast<bf16x8*>(row + (((w * 2 + 1) ^ swz(lane)) << 4)) = hi;
}

__device__ __forceinline__ void computeStep_f(const short* A, const short* B,
                                              int w, int g, int c16, f32x4 acc[4][4]) {
#pragma unroll
  for (int kk = 0; kk < 2; ++kk) {
    int slot = kk * 4 + g;
    bf16x8 b[4];
#pragma unroll
    for (int ni = 0; ni < 4; ++ni) b[ni] = *fragA(B, ni * 16 + c16, slot);
#pragma unroll
    for (int mi = 0; mi < 4; ++mi) {
      bf16x8 a = *fragA(A, w * 64 + mi * 16 + c16, slot);
#pragma unroll
      for (int ni = 0; ni < 4; ++ni)
        acc[mi][ni] = __builtin_amdgcn_mfma_f32_16x16x32_bf16(a, b[ni], acc[mi][ni], 0, 0, 0);
    }
  }
}

template<bool GATE>
__global__ __launch_bounds__(256, 3)
void gemm_direct(const short* __restrict__ xb, const float* __restrict__ W,
                 const float* __restrict__ bias, float* __restrict__ Cout,
                 float* __restrict__ partials, int N, int ntiles) {
  __shared__ __align__(16) short As[256 * 64];
  __shared__ __align__(16) short Bs[64 * 64];
  const int tid = threadIdx.x;
  const int lane = tid & 63, w = tid >> 6;
  const int g = lane >> 4, c16 = lane & 15;
  const int n0 = blockIdx.x * 64;
  const bool okc = (n0 + lane) < N;

  f32x4 acc[4][4] = {};
  float vbA[16], vbN[16];
  loadB_f(W, N, okc, n0, w, lane, 0, vbA);

#pragma unroll 1
  for (int t = 0; t < 16; ++t) {
    asm volatile("" ::: "memory");
    __builtin_amdgcn_s_barrier();
    asm volatile("" ::: "memory");
    gloadA(xb, w, lane, t, As);
    asm volatile("" ::: "memory");
    int tn = (t < 15) ? t + 1 : 15;
    loadB_f(W, N, okc, n0, w, lane, tn, vbN);
    transB_f(vbA, Bs, w, lane);
    asm volatile("s_waitcnt vmcnt(16) lgkmcnt(0)" ::: "memory");
    __builtin_amdgcn_s_barrier();
    asm volatile("" ::: "memory");
    computeStep_f(As, Bs, w, g, c16, acc);
#pragma unroll
    for (int i = 0; i < 16; ++i) vbA[i] = vbN[i];
  }

#pragma unroll
  for (int mi = 0; mi < 4; ++mi) {
#pragma unroll
    for (int r = 0; r < 4; ++r) {
      int row = w * 64 + mi * 16 + g * 4 + r;
      float vals[4];
      float pm = -3.0e38f;
#pragma unroll
      for (int ni = 0; ni < 4; ++ni) {
        int col = n0 + ni * 16 + c16;
        bool ok2 = col < N;
        float bv = ok2 ? bias[col] : 0.f;
        float v = acc[mi][ni][r] + bv;
        if (GATE) v = tanhf(v);
        vals[ni] = v;
        if (ok2) { Cout[(size_t)row * N + col] = v; pm = fmaxf(pm, v); }
      }
      if (!GATE) {
        float ps = 0.f;
#pragma unroll
        for (int ni = 0; ni < 4; ++ni) {
          int col = n0 + ni * 16 + c16;
          if (col < N) ps += expf(vals[ni] - pm);
        }
#pragma unroll
        for (int o = 1; o < 16; o <<= 1) {
          float m2 = __shfl_xor(pm, o, 64);
          float s2 = __shfl_xor(ps, o, 64);
          float mn = fmaxf(pm, m2);
          ps = ps * expf(pm - mn) + s2 * expf(m2 - mn);
          pm = mn;
        }
        if (c16 == 0) {
          partials[((size_t)row * ntiles + blockIdx.x) * 2 + 0] = pm;
          partials[((size_t)row * ntiles + blockIdx.x) * 2 + 1] = ps;
        }
      }
    }
  }
}

// ---------------------------------------------------------------------------
// combine per-row partial (max,sum) over ntiles -> stats
// ---------------------------------------------------------------------------
__global__ __launch_bounds__(256)
void combine_stats(const float* __restrict__ partials, float* __restrict__ stats,
                   int ntiles) {
  int row = blockIdx.x, tid = threadIdx.x;
  float m = -3.0e38f, s = 0.f;
  for (int j = tid; j < ntiles; j += 256) {
    float pm = partials[((size_t)row * ntiles + j) * 2 + 0];
    float ps = partials[((size_t)row * ntiles + j) * 2 + 1];
    float mn = fmaxf(m, pm);
    s = s * expf(m - mn) + ps * expf(pm - mn);
    m = mn;
  }
#pragma unroll
  for (int o = 1; o < 64; o <<= 1) {
    float m2 = __shfl_xor(m, o, 64);
    float s2 = __shfl_xor(s, o, 64);
    float mn = fmaxf(m, m2);
    s = s * expf(m - mn) + s2 * expf(m2 - mn);
    m = mn;
  }
  __shared__ float lm[4], ls[4];
  int wv = tid >> 6, ln = tid & 63;
  if (ln == 0) { lm[wv] = m; ls[wv] = s; }
  __syncthreads();
  if (tid == 0) {
    float M = lm[0], S = ls[0];
    for (int k = 1; k < 4; ++k) {
      float mn = fmaxf(M, lm[k]);
      S = S * expf(M - mn) + ls[k] * expf(lm[k] - mn);
      M = mn;
    }
    stats[row * 2 + 0] = M;
    stats[row * 2 + 1] = S;
  }
}

// ---------------------------------------------------------------------------
// mix = softmax2(h @ W2 + b2), one block per row
// ---------------------------------------------------------------------------
__global__ __launch_bounds__(256)
void gate_mix(const float* __restrict__ h, const float* __restrict__ W2,
              const float* __restrict__ b2, float* __restrict__ mix) {
  const int row = blockIdx.x;
  const int tid = threadIdx.x;
  float g0 = 0.f, g1 = 0.f;
  for (int j = tid; j < ND; j += 256) {
    float hv = h[row * ND + j];
    g0 += hv * W2[j * 2 + 0];
    g1 += hv * W2[j * 2 + 1];
  }
  for (int o = 32; o > 0; o >>= 1) {
    g0 += __shfl_down(g0, o, 64);
    g1 += __shfl_down(g1, o, 64);
  }
  __shared__ float l0[4], l1[4];
  int wid = tid >> 6, lane = tid & 63;
  if (lane == 0) { l0[wid] = g0; l1[wid] = g1; }
  __syncthreads();
  if (tid == 0) {
    float a = l0[0] + l0[1] + l0[2] + l0[3] + b2[0];
    float c = l1[0] + l1[1] + l1[2] + l1[3] + b2[1];
    float m = fmaxf(a, c);
    float e0 = expf(a - m), e1 = expf(c - m);
    float inv = 1.f / (e0 + e1);
    mix[row * 2 + 0] = e0 * inv;
    mix[row * 2 + 1] = e1 * inv;
  }
}

// ---------------------------------------------------------------------------
// alphas = softmax(scores) rowwise
// ---------------------------------------------------------------------------
__global__ __launch_bounds__(256)
void softmax_scores(const float* __restrict__ scores, float* __restrict__ alphas) {
  const int row = blockIdx.x;
  const int tid = threadIdx.x;
  float v0 = scores[row * NS + tid];
  float v1 = scores[row * NS + tid + 256];
  float m = fmaxf(v0, v1);
  for (int o = 32; o > 0; o >>= 1) m = fmaxf(m, __shfl_down(m, o, 64));
  __shared__ float lm[4], ls[4];
  int wid = tid >> 6, lane = tid & 63;
  if (lane == 0) lm[wid] = m;
  __syncthreads();
  float mAll = fmaxf(fmaxf(lm[0], lm[1]), fmaxf(lm[2], lm[3]));
  float e0 = expf(v0 - mAll), e1 = expf(v1 - mAll);
  float s = e0 + e1;
  for (int o = 32; o > 0; o >>= 1) s += __shfl_down(s, o, 64);
  if (lane == 0) ls[wid] = s;
  __syncthreads();
  float inv = 1.f / (ls[0] + ls[1] + ls[2] + ls[3]);
  alphas[row * NS + tid] = e0 * inv;
  alphas[row * NS + tid + 256] = e1 * inv;
}

// ---------------------------------------------------------------------------
// out = exp(logit - m)/s * mix0   (in-place on d_out)
// ---------------------------------------------------------------------------
__global__ __launch_bounds__(256)
void finalize_gen(float* __restrict__ out, const float* __restrict__ stats,
                  const float* __restrict__ mix) {
  const int row = blockIdx.y;
  const int col = blockIdx.x * 256 + threadIdx.x;
  if (col < NV) {
    float m = stats[row * 2 + 0], s = stats[row * 2 + 1];
    float gmul = mix[row * 2 + 0];
    float x = out[(size_t)row * NV + col];
    out[(size_t)row * NV + col] = expf(x - m) * (gmul / s);
  }
}

// ---------------------------------------------------------------------------
// out[row, ctx_ids[row,s]] += alphas[row,s] * mix1[row]
// ---------------------------------------------------------------------------
__global__ __launch_bounds__(512)
void scatter_copy(float* __restrict__ out, const float* __restrict__ alphas,
                  const int* __restrict__ ids, const float* __restrict__ mix) {
  const int row = blockIdx.x;
  const int t = threadIdx.x;
  float a = alphas[row * NS + t] * mix[row * 2 + 1];
  atomicAdd(&out[(size_t)row * NV + ids[row * NS + t]], a);
}

extern "C" void kernel_launch(void* const* d_in, const int* in_sizes, int n_in,
                              void* d_out, int out_size, void* d_ws, size_t ws_size,
                              hipStream_t stream) {
  const float* x      = (const float*)d_in[0];
  const float* scores = (const float*)d_in[1];
  const int*   ctx    = (const int*)d_in[2];
  const float* Wg     = (const float*)d_in[3];
  const float* bg     = (const float*)d_in[4];
  const float* W1     = (const float*)d_in[5];
  const float* b1     = (const float*)d_in[6];
  const float* W2     = (const float*)d_in[7];
  const float* b2     = (const float*)d_in[8];
  float* out = (float*)d_out;

  // workspace layout
  const size_t xb_sz    = 512 * 1024;
  const size_t pwg_sz   = (size_t)NTILES_V * 16 * BSTEP;   // ~115.9 MB
  const size_t pw1_sz   = (size_t)NTILES_D * 16 * BSTEP;   // ~2.36 MB
  const size_t part_sz  = (size_t)NB * NTILES_V * 2 * 4;
  const size_t small_sz = (size_t)(NB * 2 + NB * 2 + NB * NS + NB * ND) * 4;
  const size_t need     = xb_sz + pwg_sz + pw1_sz + part_sz + small_sz;

  short* xb = (short*)d_ws;
  char* base = (char*)d_ws + xb_sz;

  if (ws_size >= need) {
    short* packedWg = (short*)base;
    short* packedW1 = (short*)(base + pwg_sz);
    float* partials = (float*)(base + pwg_sz + pw1_sz);
    float* mix      = partials + (size_t)NB * NTILES_V * 2;
    float* stats    = mix + NB * 2;
    float* alphas   = stats + NB * 2;
    float* h        = alphas + NB * NS;

    prep_x<<<128, 256, 0, stream>>>(x, xb);
    prep_w<<<dim3(NTILES_D, 16), 256, 0, stream>>>(W1, packedW1, ND);
    prep_w<<<dim3(NTILES_V, 16), 256, 0, stream>>>(Wg, packedWg, NV);
    gemm_packed<true><<<NTILES_D, 256, 0, stream>>>(xb, packedW1, b1, h, nullptr, ND, NTILES_D);
    gate_mix<<<NB, 256, 0, stream>>>(h, W2, b2, mix);
    softmax_scores<<<NB, 256, 0, stream>>>(scores, alphas);
    gemm_packed<false><<<NTILES_V, 256, 0, stream>>>(xb, packedWg, bg, out, partials, NV, NTILES_V);
    combine_stats<<<NB, 256, 0, stream>>>(partials, stats, NTILES_V);
    finalize_gen<<<dim3((NV + 255) / 256, NB), 256, 0, stream>>>(out, stats, mix);
    scatter_copy<<<NB, NS, 0, stream>>>(out, alphas, ctx, mix);
  } else {
    // fallback: R5 path (no packed W)
    float* partials = (float*)base;
    float* mix      = partials + (size_t)NB * NTILES_V * 2;
    float* stats    = mix + NB * 2;
    float* alphas   = stats + NB * 2;
    float* h        = alphas + NB * NS;

    prep_x<<<128, 256, 0, stream>>>(x, xb);
    gemm_direct<true><<<NTILES_D, 256, 0, stream>>>(xb, W1, b1, h, nullptr, ND, NTILES_D);
    gate_mix<<<NB, 256, 0, stream>>>(h, W2, b2, mix);
    softmax_scores<<<NB, 256, 0, stream>>>(scores, alphas);
    gemm_direct<false><<<NTILES_V, 256, 0, stream>>>(xb, Wg, bg, out, partials, NV, NTILES_V);
    combine_stats<<<NB, 256, 0, stream>>>(partials, stats, NTILES_V);
    finalize_gen<<<dim3((NV + 255) / 256, NB), 256, 0, stream>>>(out, stats, mix);
    scatter_copy<<<NB, NS, 0, stream>>>(out, alphas, ctx, mix);
  }
}

// Round 7
// 189.065 us; speedup vs baseline: 1.4656x; 1.4656x over previous
//
#include <hip/hip_runtime.h>
#include <hip/hip_bf16.h>
#include <math.h>

constexpr int NB = 256;    // batch
constexpr int NS = 512;    // source positions
constexpr int ND = 1024;   // hidden
constexpr int NV = 50257;  // vocab
constexpr int NBLK_V = (NV + 255) / 256;   // 197 column-blocks of 256
constexpr int NTILE2 = NBLK_V * 4;         // 788 partial tiles (64-col) per row

typedef __attribute__((ext_vector_type(8))) short bf16x8;
typedef __attribute__((ext_vector_type(4))) float f32x4;

__device__ __forceinline__ short f2bf(float f) {
  unsigned u = __builtin_bit_cast(unsigned, f);
  u = (u + 0x7FFFu + ((u >> 16) & 1u)) >> 16;   // RNE
  return (short)u;
}

// chunk position = slot ^ swz(row); self-inverse, same on write+read.
__device__ __forceinline__ int swz(int r) { return (r & 7) ^ ((r >> 3) & 1); }

__device__ __forceinline__ const bf16x8* frag(const short* base, int r, int slot) {
  return reinterpret_cast<const bf16x8*>(
      reinterpret_cast<const char*>(base) + r * 128 + ((slot ^ swz(r)) << 4));
}

__device__ __forceinline__ void async_copy16(const void* gsrc, void* ldsdst) {
  __builtin_amdgcn_global_load_lds(
      (const __attribute__((address_space(1))) unsigned int*)gsrc,
      (__attribute__((address_space(3))) unsigned int*)ldsdst, 16, 0, 0);
}

// ---------------------------------------------------------------------------
// prep_x: xb[m][kt][chunkpos] bf16, pre-swizzled for linear global_load_lds.
// ---------------------------------------------------------------------------
__global__ __launch_bounds__(256)
void prep_x(const float* __restrict__ x, short* __restrict__ xb) {
  int idx = blockIdx.x * 256 + threadIdx.x;      // 32768 chunks
  int m = idx >> 7, kt = (idx >> 3) & 15, slot = idx & 7;
  const float4* src = reinterpret_cast<const float4*>(x + m * ND + kt * 64 + slot * 8);
  float4 f0 = src[0], f1 = src[1];
  bf16x8 v = { f2bf(f0.x), f2bf(f0.y), f2bf(f0.z), f2bf(f0.w),
               f2bf(f1.x), f2bf(f1.y), f2bf(f1.z), f2bf(f1.w) };
  *reinterpret_cast<bf16x8*>(reinterpret_cast<char*>(xb) +
      m * 2048 + kt * 128 + ((slot ^ swz(m)) << 4)) = v;
}

// ---------------------------------------------------------------------------
// gemm2: C[256,N] = act(x @ W + bias). BM=256, BN=256, BK=64, 1024 threads
// (16 waves, 4Mx4N wave grid, 64x64 per wave). Full LDS double-buffer
// (A 2x32KB + B 2x32KB = 128KB), ONE barrier per K-step.
// A: global_load_lds from pre-swizzled xb (L2). B: 16 coalesced dwords/thread
// (1KB-contiguous per 4-wave row-visit) -> f2bf -> 2x ds_write_b128; single
// 16-reg buffer recycled (consume B(t+1), reload B(t+2)); loads stay in
// flight across the barrier via counted vmcnt(16) (drains only the 2 A-DMAs).
// ---------------------------------------------------------------------------
__device__ __forceinline__ void loadB16(const float* __restrict__ W, int N, bool okB,
                                        int colB, int rg, int t, float v[16]) {
#pragma unroll
  for (int i = 0; i < 16; ++i)
    v[i] = okB ? W[(size_t)(t * 64 + rg * 16 + i) * N + colB] : 0.f;
}

__device__ __forceinline__ void gloadA2(const short* __restrict__ xb,
                                        int w, int lane, int t, short* AsN) {
#pragma unroll
  for (int j = 0; j < 2; ++j) {
    int c = w * 128 + j * 64 + lane;             // 0..2047
    int ml = c >> 3, p = c & 7;
    const char* src = reinterpret_cast<const char*>(xb) +
        (ml << 11) + (t << 7) + (p << 4);
    async_copy16(src, reinterpret_cast<char*>(AsN) + (c << 4));
  }
}

__device__ __forceinline__ void transB2(const float v[16], short* BsN, int n, int rg) {
  bf16x8 lo = { f2bf(v[0]), f2bf(v[1]), f2bf(v[2]), f2bf(v[3]),
                f2bf(v[4]), f2bf(v[5]), f2bf(v[6]), f2bf(v[7]) };
  bf16x8 hi = { f2bf(v[8]), f2bf(v[9]), f2bf(v[10]), f2bf(v[11]),
                f2bf(v[12]), f2bf(v[13]), f2bf(v[14]), f2bf(v[15]) };
  char* row = reinterpret_cast<char*>(BsN) + n * 128;
  *reinterpret_cast<bf16x8*>(row + (((rg * 2 + 0) ^ swz(n)) << 4)) = lo;
  *reinterpret_cast<bf16x8*>(row + (((rg * 2 + 1) ^ swz(n)) << 4)) = hi;
}

__device__ __forceinline__ void computeStep2(const short* A, const short* B,
                                             int wr, int wc, int g, int c16,
                                             f32x4 acc[4][4]) {
#pragma unroll
  for (int kk = 0; kk < 2; ++kk) {
    int slot = kk * 4 + g;
    bf16x8 b[4];
#pragma unroll
    for (int ni = 0; ni < 4; ++ni) b[ni] = *frag(B, wc * 64 + ni * 16 + c16, slot);
#pragma unroll
    for (int mi = 0; mi < 4; ++mi) {
      bf16x8 a = *frag(A, wr * 64 + mi * 16 + c16, slot);
#pragma unroll
      for (int ni = 0; ni < 4; ++ni)
        acc[mi][ni] = __builtin_amdgcn_mfma_f32_16x16x32_bf16(a, b[ni], acc[mi][ni], 0, 0, 0);
    }
  }
}

template<bool GATE>
__global__ __launch_bounds__(1024, 1)
void gemm2(const short* __restrict__ xb, const float* __restrict__ W,
           const float* __restrict__ bias, float* __restrict__ Cout,
           float* __restrict__ partials, int N, int ntiles) {
  __shared__ __align__(16) short As[2][256 * 64];  // 2 x 32 KB
  __shared__ __align__(16) short Bs[2][256 * 64];  // 2 x 32 KB
  const int tid = threadIdx.x;
  const int lane = tid & 63, w = tid >> 6;
  const int wr = w >> 2, wc = w & 3;
  const int g = lane >> 4, c16 = lane & 15;
  const int n0 = blockIdx.x * 256;
  const int nB = tid & 255, rg = tid >> 8;
  const int colB = n0 + nB;
  const bool okB = colB < N;

  f32x4 acc[4][4] = {};
  float vb[16];

  // prologue: B(0) staged, B(1) in flight, A(0) staged.
  loadB16(W, N, okB, colB, rg, 0, vb);
  gloadA2(xb, w, lane, 0, As[0]);
  asm volatile("" ::: "memory");
  transB2(vb, Bs[0], nB, rg);                  // waits the 16 B(0) loads
  asm volatile("" ::: "memory");
  loadB16(W, N, okB, colB, rg, 1, vb);         // B(1) in flight
  asm volatile("s_waitcnt vmcnt(16) lgkmcnt(0)" ::: "memory");  // drain 2 DMAs
  __builtin_amdgcn_s_barrier();

#pragma unroll 1
  for (int t = 0; t < 16; ++t) {
    const int cur = t & 1, nxt = cur ^ 1;
    const int tp1 = (t < 15) ? t + 1 : 15;     // clamp: redundant re-stage, harmless
    const int tp2 = (t < 14) ? t + 2 : 15;
    gloadA2(xb, w, lane, tp1, As[nxt]);        // 2 DMA (L2-resident xb)
    asm volatile("" ::: "memory");             // pin: DMA before B issue
    transB2(vb, Bs[nxt], nB, rg);              // consume B(t+1) regs
    asm volatile("" ::: "memory");
    loadB16(W, N, okB, colB, rg, tp2, vb);     // reload same regs with B(t+2)
    asm volatile("" ::: "memory");
    computeStep2(As[cur], Bs[cur], wr, wc, g, c16, acc);
    asm volatile("s_waitcnt vmcnt(16) lgkmcnt(0)" ::: "memory");  // drain DMAs only
    __builtin_amdgcn_s_barrier();
  }

  // epilogue: C/D layout col = lane&15, row = (lane>>4)*4 + reg
#pragma unroll
  for (int mi = 0; mi < 4; ++mi) {
#pragma unroll
    for (int r = 0; r < 4; ++r) {
      int row = wr * 64 + mi * 16 + g * 4 + r;
      float vals[4];
      float pm = -3.0e38f;
#pragma unroll
      for (int ni = 0; ni < 4; ++ni) {
        int col = n0 + wc * 64 + ni * 16 + c16;
        bool ok2 = col < N;
        float bv = ok2 ? bias[col] : 0.f;
        float v = acc[mi][ni][r] + bv;
        if (GATE) v = tanhf(v);
        vals[ni] = v;
        if (ok2) {
          Cout[(size_t)row * N + col] = v;
          pm = fmaxf(pm, v);
        }
      }
      if (!GATE) {
        float ps = 0.f;
#pragma unroll
        for (int ni = 0; ni < 4; ++ni) {
          int col = n0 + wc * 64 + ni * 16 + c16;
          if (col < N) ps += expf(vals[ni] - pm);
        }
#pragma unroll
        for (int o = 1; o < 16; o <<= 1) {
          float m2 = __shfl_xor(pm, o, 64);
          float s2 = __shfl_xor(ps, o, 64);
          float mn = fmaxf(pm, m2);
          ps = ps * expf(pm - mn) + s2 * expf(m2 - mn);
          pm = mn;
        }
        if (c16 == 0) {
          size_t idx = (size_t)row * ntiles + blockIdx.x * 4 + wc;
          partials[idx * 2 + 0] = pm;
          partials[idx * 2 + 1] = ps;
        }
      }
    }
  }
}

// ---------------------------------------------------------------------------
// combine per-row partial (max,sum) over ntiles -> stats
// ---------------------------------------------------------------------------
__global__ __launch_bounds__(256)
void combine_stats(const float* __restrict__ partials, float* __restrict__ stats,
                   int ntiles) {
  int row = blockIdx.x, tid = threadIdx.x;
  float m = -3.0e38f, s = 0.f;
  for (int j = tid; j < ntiles; j += 256) {
    float pm = partials[((size_t)row * ntiles + j) * 2 + 0];
    float ps = partials[((size_t)row * ntiles + j) * 2 + 1];
    float mn = fmaxf(m, pm);
    s = s * expf(m - mn) + ps * expf(pm - mn);
    m = mn;
  }
#pragma unroll
  for (int o = 1; o < 64; o <<= 1) {
    float m2 = __shfl_xor(m, o, 64);
    float s2 = __shfl_xor(s, o, 64);
    float mn = fmaxf(m, m2);
    s = s * expf(m - mn) + s2 * expf(m2 - mn);
    m = mn;
  }
  __shared__ float lm[4], ls[4];
  int wv = tid >> 6, ln = tid & 63;
  if (ln == 0) { lm[wv] = m; ls[wv] = s; }
  __syncthreads();
  if (tid == 0) {
    float M = lm[0], S = ls[0];
    for (int k = 1; k < 4; ++k) {
      float mn = fmaxf(M, lm[k]);
      S = S * expf(M - mn) + ls[k] * expf(lm[k] - mn);
      M = mn;
    }
    stats[row * 2 + 0] = M;
    stats[row * 2 + 1] = S;
  }
}

// ---------------------------------------------------------------------------
// mix = softmax2(h @ W2 + b2), one block per row
// ---------------------------------------------------------------------------
__global__ __launch_bounds__(256)
void gate_mix(const float* __restrict__ h, const float* __restrict__ W2,
              const float* __restrict__ b2, float* __restrict__ mix) {
  const int row = blockIdx.x;
  const int tid = threadIdx.x;
  float g0 = 0.f, g1 = 0.f;
  for (int j = tid; j < ND; j += 256) {
    float hv = h[row * ND + j];
    g0 += hv * W2[j * 2 + 0];
    g1 += hv * W2[j * 2 + 1];
  }
  for (int o = 32; o > 0; o >>= 1) {
    g0 += __shfl_down(g0, o, 64);
    g1 += __shfl_down(g1, o, 64);
  }
  __shared__ float l0[4], l1[4];
  int wid = tid >> 6, lane = tid & 63;
  if (lane == 0) { l0[wid] = g0; l1[wid] = g1; }
  __syncthreads();
  if (tid == 0) {
    float a = l0[0] + l0[1] + l0[2] + l0[3] + b2[0];
    float c = l1[0] + l1[1] + l1[2] + l1[3] + b2[1];
    float m = fmaxf(a, c);
    float e0 = expf(a - m), e1 = expf(c - m);
    float inv = 1.f / (e0 + e1);
    mix[row * 2 + 0] = e0 * inv;
    mix[row * 2 + 1] = e1 * inv;
  }
}

// ---------------------------------------------------------------------------
// alphas = softmax(scores) rowwise
// ---------------------------------------------------------------------------
__global__ __launch_bounds__(256)
void softmax_scores(const float* __restrict__ scores, float* __restrict__ alphas) {
  const int row = blockIdx.x;
  const int tid = threadIdx.x;
  float v0 = scores[row * NS + tid];
  float v1 = scores[row * NS + tid + 256];
  float m = fmaxf(v0, v1);
  for (int o = 32; o > 0; o >>= 1) m = fmaxf(m, __shfl_down(m, o, 64));
  __shared__ float lm[4], ls[4];
  int wid = tid >> 6, lane = tid & 63;
  if (lane == 0) lm[wid] = m;
  __syncthreads();
  float mAll = fmaxf(fmaxf(lm[0], lm[1]), fmaxf(lm[2], lm[3]));
  float e0 = expf(v0 - mAll), e1 = expf(v1 - mAll);
  float s = e0 + e1;
  for (int o = 32; o > 0; o >>= 1) s += __shfl_down(s, o, 64);
  if (lane == 0) ls[wid] = s;
  __syncthreads();
  float inv = 1.f / (ls[0] + ls[1] + ls[2] + ls[3]);
  alphas[row * NS + tid] = e0 * inv;
  alphas[row * NS + tid + 256] = e1 * inv;
}

// ---------------------------------------------------------------------------
// out = exp(logit - m)/s * mix0   (in-place on d_out)
// ---------------------------------------------------------------------------
__global__ __launch_bounds__(256)
void finalize_gen(float* __restrict__ out, const float* __restrict__ stats,
                  const float* __restrict__ mix) {
  const int row = blockIdx.y;
  const int col = blockIdx.x * 256 + threadIdx.x;
  if (col < NV) {
    float m = stats[row * 2 + 0], s = stats[row * 2 + 1];
    float gmul = mix[row * 2 + 0];
    float x = out[(size_t)row * NV + col];
    out[(size_t)row * NV + col] = expf(x - m) * (gmul / s);
  }
}

// ---------------------------------------------------------------------------
// out[row, ctx_ids[row,s]] += alphas[row,s] * mix1[row]
// ---------------------------------------------------------------------------
__global__ __launch_bounds__(512)
void scatter_copy(float* __restrict__ out, const float* __restrict__ alphas,
                  const int* __restrict__ ids, const float* __restrict__ mix) {
  const int row = blockIdx.x;
  const int t = threadIdx.x;
  float a = alphas[row * NS + t] * mix[row * 2 + 1];
  atomicAdd(&out[(size_t)row * NV + ids[row * NS + t]], a);
}

extern "C" void kernel_launch(void* const* d_in, const int* in_sizes, int n_in,
                              void* d_out, int out_size, void* d_ws, size_t ws_size,
                              hipStream_t stream) {
  const float* x      = (const float*)d_in[0];
  const float* scores = (const float*)d_in[1];
  const int*   ctx    = (const int*)d_in[2];
  const float* Wg     = (const float*)d_in[3];
  const float* bg     = (const float*)d_in[4];
  const float* W1     = (const float*)d_in[5];
  const float* b1     = (const float*)d_in[6];
  const float* W2     = (const float*)d_in[7];
  const float* b2     = (const float*)d_in[8];
  float* out = (float*)d_out;

  short* xb       = (short*)d_ws;                                   // 512 KB
  float* partials = (float*)((char*)d_ws + 512 * 1024);             // 256*788*2 f32
  float* mix      = partials + (size_t)NB * NTILE2 * 2;
  float* stats    = mix + NB * 2;
  float* alphas   = stats + NB * 2;
  float* h        = alphas + NB * NS;

  // x -> bf16, pre-swizzled for linear global_load_lds staging
  prep_x<<<128, 256, 0, stream>>>(x, xb);
  // h = tanh(x @ W1 + b1)   (4 column-blocks of 256)
  gemm2<true><<<ND / 256, 1024, 0, stream>>>(xb, W1, b1, h, nullptr, ND, 16);
  // mix = softmax2(h @ W2 + b2)
  gate_mix<<<NB, 256, 0, stream>>>(h, W2, b2, mix);
  // alphas = softmax(scores)
  softmax_scores<<<NB, 256, 0, stream>>>(scores, alphas);
  // logits = x @ Wg + bg -> d_out, fused per-row partial max/sum
  gemm2<false><<<NBLK_V, 1024, 0, stream>>>(xb, Wg, bg, out, partials, NV, NTILE2);
  // combine partials -> stats
  combine_stats<<<NB, 256, 0, stream>>>(partials, stats, NTILE2);
  // out = softmax * mix0 (in place)
  finalize_gen<<<dim3((NV + 255) / 256, NB), 256, 0, stream>>>(out, stats, mix);
  // scatter copy distribution
  scatter_copy<<<NB, NS, 0, stream>>>(out, alphas, ctx, mix);
}